// Round 4
// baseline (366.323 us; speedup 1.0000x reference)
//
#include <hip/hip_runtime.h>

// ---------------------------------------------------------------------------
// VisualContrastiveLoss on MI355X
// loss = C + mean_i log(Z_i) - mean_i sim[i, lab_i],  C = 1/0.07
//   Z_i = sum_j exp(sim_ij - C)   (fixed shift: dots bounded by 1)
//   sim = (f f^T)/0.07, f = row-normalized visual_feat
// R4: MX-fp8 (e4m3, scale=1) via mfma_scale_f32_16x16x128_f8f6f4, with the
//     B-fragment loop split to bv[2] so the live register set fits the
//     256-unified-reg/wave budget at 2 waves/SIMD (R3 spilled: 1 GB scratch
//     traffic, 256 us). acc[4][8]=128 AGPR + ~110 VGPR = ~240 <= 256.
//     Exact-diagonal correction via captured D[i] (validated in R3).
// ---------------------------------------------------------------------------

typedef int i32x8 __attribute__((ext_vector_type(8)));
typedef float f32x4 __attribute__((ext_vector_type(4)));

#define B_N 8192
#define D_K 512
#define ROWB 512  // bytes per fp8 row
#define INVT 14.285714285714286f
// (1/0.07) * log2(e)
#define SCALE_LOG2 20.609929155556622f

static __device__ __forceinline__ void load16_to_lds(const void* g, void* l) {
  __builtin_amdgcn_global_load_lds(
      (const __attribute__((address_space(1))) unsigned int*)g,
      (__attribute__((address_space(3))) unsigned int*)l, 16, 0, 0);
}

// ---- K1: 4 waves/block, one wave per row; normalize fp32 -> fp8 e4m3 --------
__global__ __launch_bounds__(256)
void norm_kernel(const float* __restrict__ x,
                 unsigned char* __restrict__ fQ,
                 float* __restrict__ Z) {
  const int row = blockIdx.x * 4 + (threadIdx.x >> 6);
  const int lane = threadIdx.x & 63;
  const float4* xr = (const float4*)(x + (size_t)row * D_K);
  float4 a = xr[2 * lane];
  float4 b = xr[2 * lane + 1];
  float s = a.x * a.x + a.y * a.y + a.z * a.z + a.w * a.w +
            b.x * b.x + b.y * b.y + b.z * b.z + b.w * b.w;
#pragma unroll
  for (int off = 1; off < 64; off <<= 1) s += __shfl_xor(s, off);
  const float inv = 1.0f / fmaxf(sqrtf(s), 1e-12f);
  int lo = 0, hi = 0;
  lo = __builtin_amdgcn_cvt_pk_fp8_f32(a.x * inv, a.y * inv, lo, false);
  lo = __builtin_amdgcn_cvt_pk_fp8_f32(a.z * inv, a.w * inv, lo, true);
  hi = __builtin_amdgcn_cvt_pk_fp8_f32(b.x * inv, b.y * inv, hi, false);
  hi = __builtin_amdgcn_cvt_pk_fp8_f32(b.z * inv, b.w * inv, hi, true);
  int2 p; p.x = lo; p.y = hi;
  ((int2*)(fQ + (size_t)row * ROWB))[lane] = p;
  if (lane == 0) Z[row] = 0.0f;
}

// ---- K2: fused fp8 similarity + partial softmax-denominator -----------------
// grid (64, 8): blockIdx.x -> 128-row tile, blockIdx.y -> 1024-col j-range
// (4 jt of 256 cols). 4 waves 2x2; wave owns 64x128 C via 4x8 frags of
// 16x16x128 MX-fp8 MFMA (scale=1). K staged in 4 chunks of 128 B/row.
// 16B LDS granules XOR-swizzled by (row&7) on the global source.
__global__ __launch_bounds__(256, 2)
void sim_kernel(const unsigned char* __restrict__ fQ,
                float* __restrict__ Z, float* __restrict__ T01,
                float* __restrict__ D) {
  __shared__ unsigned char ldsA[128 * 128];   // 16 KB
  __shared__ unsigned char ldsB[256 * 128];   // 32 KB

  const int tid = threadIdx.x;
  const int lane = tid & 63;
  const int w = tid >> 6;
  const int wm = w & 1;       // wave row strip (0/1) -> rows wm*64..
  const int wn = w >> 1;      // wave col strip (0/1) -> cols wn*128..
  const int I0 = blockIdx.x * 128;
  const int Jbase = blockIdx.y * 1024;

  // staging lane geometry: 8 rows x 8 granules(16B) per instruction
  const int srow = lane >> 3;                 // 0..7
  const int sg = (lane & 7) ^ srow;           // swizzled source granule
  const size_t sOff = (size_t)srow * ROWB + sg * 16;  // bytes

  // fragment-read lane geometry
  const int fr = lane & 15;   // M/N index within 16
  const int q = lane >> 4;    // quad -> k chunk of 32B
  const int swz = fr & 7;     // row&7 of the frag row

  // precomputed LDS frag base pointers (byte addresses)
  const unsigned char* raBase = ldsA + (wm * 64 + fr) * 128;
  const unsigned char* rbBase = ldsB + (wn * 128 + fr) * 128;
  const int off0 = ((2 * q) ^ swz) * 16;
  const int off1 = ((2 * q + 1) ^ swz) * 16;

  float Zp[4][4];
#pragma unroll
  for (int m = 0; m < 4; ++m)
#pragma unroll
    for (int r = 0; r < 4; ++r) Zp[m][r] = 0.0f;

  for (int jt = 0; jt < 4; ++jt) {
    const int J0 = Jbase + jt * 256;
    f32x4 acc[4][8];
#pragma unroll
    for (int m = 0; m < 4; ++m)
#pragma unroll
      for (int n = 0; n < 8; ++n) acc[m][n] = (f32x4){0.f, 0.f, 0.f, 0.f};

    for (int kk = 0; kk < 4; ++kk) {
      const int k0 = kk * 128;  // byte offset into row
      {  // A: 128 rows, wave stages rows w*32..+31 (4 instrs)
        const unsigned char* gA = fQ + (size_t)(I0 + w * 32) * ROWB + k0 + sOff;
        unsigned char* lA = ldsA + (w * 32) * 128;
#pragma unroll
        for (int rr = 0; rr < 32; rr += 8)
          load16_to_lds(gA + (size_t)rr * ROWB, lA + rr * 128);
      }
      {  // B: 256 rows, wave stages rows w*64..+63 (8 instrs)
        const unsigned char* gB = fQ + (size_t)(J0 + w * 64) * ROWB + k0 + sOff;
        unsigned char* lB = ldsB + (w * 64) * 128;
#pragma unroll
        for (int rr = 0; rr < 64; rr += 8)
          load16_to_lds(gB + (size_t)rr * ROWB, lB + rr * 128);
      }
      __syncthreads();

      i32x8 av[4];
#pragma unroll
      for (int m = 0; m < 4; ++m) {
        const unsigned char* ra = raBase + m * 16 * 128;
        int4 r0 = *(const int4*)(ra + off0);
        int4 r1 = *(const int4*)(ra + off1);
        av[m] = (i32x8){r0.x, r0.y, r0.z, r0.w, r1.x, r1.y, r1.z, r1.w};
      }
#pragma unroll
      for (int nh = 0; nh < 4; ++nh) {  // bv[2] at a time: fits registers
        i32x8 bv[2];
#pragma unroll
        for (int n = 0; n < 2; ++n) {
          const unsigned char* rb = rbBase + (nh * 2 + n) * 16 * 128;
          int4 r0 = *(const int4*)(rb + off0);
          int4 r1 = *(const int4*)(rb + off1);
          bv[n] = (i32x8){r0.x, r0.y, r0.z, r0.w, r1.x, r1.y, r1.z, r1.w};
        }
#pragma unroll
        for (int m = 0; m < 4; ++m)
#pragma unroll
          for (int n = 0; n < 2; ++n)
            acc[m][nh * 2 + n] = __builtin_amdgcn_mfma_scale_f32_16x16x128_f8f6f4(
                av[m], bv[n], acc[m][nh * 2 + n], 0, 0, 0, 127, 0, 127);
      }
      __syncthreads();
    }

    // capture sim[:,0] and sim[:,1] (cols 0,1: j-tile 0, wn==0, n==0, fr<2)
    if (blockIdx.y == 0 && jt == 0 && wn == 0 && fr < 2) {
#pragma unroll
      for (int m = 0; m < 4; ++m)
#pragma unroll
        for (int r = 0; r < 4; ++r) {
          const int row = I0 + wm * 64 + m * 16 + q * 4 + r;
          T01[row * 2 + fr] = acc[m][0][r] * INVT;
        }
    }

    // capture the computed diagonal dot (for exact-diag correction)
    if (blockIdx.y == (blockIdx.x >> 3) && jt == ((blockIdx.x & 7) >> 1)) {
#pragma unroll
      for (int m = 0; m < 4; ++m)
#pragma unroll
        for (int n = 0; n < 8; ++n) {
          const int col = J0 + wn * 128 + n * 16 + fr;
#pragma unroll
          for (int r = 0; r < 4; ++r) {
            const int row = I0 + wm * 64 + m * 16 + q * 4 + r;
            if (row == col) D[row] = acc[m][n][r];
          }
        }
    }

    // Z partials: exp((dot-1)/T) summed over this wave's 128 cols
#pragma unroll
    for (int m = 0; m < 4; ++m)
#pragma unroll
      for (int n = 0; n < 8; ++n)
#pragma unroll
        for (int r = 0; r < 4; ++r)
          Zp[m][r] += exp2f((acc[m][n][r] - 1.0f) * SCALE_LOG2);
  }

  // reduce Zp across the 16 col-lanes (low 4 lane bits), then atomicAdd
#pragma unroll
  for (int m = 0; m < 4; ++m)
#pragma unroll
    for (int r = 0; r < 4; ++r) {
      float v = Zp[m][r];
      v += __shfl_xor(v, 1);
      v += __shfl_xor(v, 2);
      v += __shfl_xor(v, 4);
      v += __shfl_xor(v, 8);
      if (fr == 0) atomicAdd(&Z[I0 + wm * 64 + m * 16 + q * 4 + r], v);
    }
}

// ---- K3: labels + exact-diagonal fixup + final loss reduction ---------------
__global__ __launch_bounds__(1024)
void finalize_kernel(const float* __restrict__ Z,
                     const float* __restrict__ T01,
                     const float* __restrict__ D,
                     const int* __restrict__ ids,
                     const int* __restrict__ anchor,
                     float* __restrict__ out) {
  __shared__ float red[1024];
  const int t = threadIdx.x;
  const int anchor_id = ids[anchor[0]];
  const int sameLast = (ids[B_N - 1] == anchor_id);
  const int samePrev = (ids[B_N - 2] == anchor_id);
  float sum = 0.0f;
#pragma unroll
  for (int it = 0; it < B_N / 1024; ++it) {
    const int i = it * 1024 + t;
    const int same_i = (ids[i] == anchor_id);
    const int lab = (i < B_N - 1) ? (same_i & sameLast) : (sameLast & samePrev);
    const float tt = T01[i * 2 + lab];
    // replace quantized diag contribution with the exact value exp(0)=1
    const float Zc = Z[i] - exp2f((D[i] - 1.0f) * SCALE_LOG2) + 1.0f;
    sum += tt - (INVT + logf(Zc));
  }
  red[t] = sum;
  __syncthreads();
  for (int off = 512; off > 0; off >>= 1) {
    if (t < off) red[t] += red[t + off];
    __syncthreads();
  }
  if (t == 0) out[0] = -red[0] / (float)B_N;
}

// ---------------------------------------------------------------------------
extern "C" void kernel_launch(void* const* d_in, const int* in_sizes, int n_in,
                              void* d_out, int out_size, void* d_ws, size_t ws_size,
                              hipStream_t stream) {
  const float* x = (const float*)d_in[0];
  const int* ids = (const int*)d_in[1];
  const int* anchor = (const int*)d_in[2];
  float* out = (float*)d_out;

  unsigned char* fQ = (unsigned char*)d_ws;                    // 4 MB fp8
  float* Z = (float*)((char*)d_ws + (size_t)B_N * ROWB);       // 32 KB
  float* T01 = Z + B_N;                                        // 64 KB
  float* D = T01 + 2 * B_N;                                    // 32 KB

  norm_kernel<<<B_N / 4, 256, 0, stream>>>(x, fQ, Z);
  sim_kernel<<<dim3(64, 8), 256, 0, stream>>>(fQ, Z, T01, D);
  finalize_kernel<<<1, 1024, 0, stream>>>(Z, T01, D, ids, anchor, out);
}

// Round 5
// 198.657 us; speedup vs baseline: 1.8440x; 1.8440x over previous
//
#include <hip/hip_runtime.h>

// ---------------------------------------------------------------------------
// VisualContrastiveLoss on MI355X
// loss = C + mean_i log(Z_i) - mean_i sim[i, lab_i],  C = 1/0.07
//   Z_i = sum_j exp(sim_ij - C)   (fixed shift: dots bounded by 1)
//   sim = (f f^T)/0.07, f = row-normalized visual_feat
// R5: MX-fp8 (e4m3, scale=1) via mfma_scale_f32_16x16x128_f8f6f4 with wave
//     tile 64x64 (acc[4][4]=64 regs). R3/R4 spilled ~520 MB scratch because
//     acc[4][8]=128 + i32x8 frags exceeded the 2-waves/SIMD register budget;
//     identical spill volume across frag-split variants fingered the acc.
//     Block 128x128, grid (64,8), 8 jt x 4 kk. Exact-diagonal correction
//     via captured D[i] (validated R3/R4).
// ---------------------------------------------------------------------------

typedef int i32x8 __attribute__((ext_vector_type(8)));
typedef float f32x4 __attribute__((ext_vector_type(4)));

#define B_N 8192
#define D_K 512
#define ROWB 512  // bytes per fp8 row
#define INVT 14.285714285714286f
// (1/0.07) * log2(e)
#define SCALE_LOG2 20.609929155556622f

static __device__ __forceinline__ void load16_to_lds(const void* g, void* l) {
  __builtin_amdgcn_global_load_lds(
      (const __attribute__((address_space(1))) unsigned int*)g,
      (__attribute__((address_space(3))) unsigned int*)l, 16, 0, 0);
}

// ---- K1: 4 waves/block, one wave per row; normalize fp32 -> fp8 e4m3 --------
__global__ __launch_bounds__(256)
void norm_kernel(const float* __restrict__ x,
                 unsigned char* __restrict__ fQ,
                 float* __restrict__ Z) {
  const int row = blockIdx.x * 4 + (threadIdx.x >> 6);
  const int lane = threadIdx.x & 63;
  const float4* xr = (const float4*)(x + (size_t)row * D_K);
  float4 a = xr[2 * lane];
  float4 b = xr[2 * lane + 1];
  float s = a.x * a.x + a.y * a.y + a.z * a.z + a.w * a.w +
            b.x * b.x + b.y * b.y + b.z * b.z + b.w * b.w;
#pragma unroll
  for (int off = 1; off < 64; off <<= 1) s += __shfl_xor(s, off);
  const float inv = 1.0f / fmaxf(sqrtf(s), 1e-12f);
  int lo = 0, hi = 0;
  lo = __builtin_amdgcn_cvt_pk_fp8_f32(a.x * inv, a.y * inv, lo, false);
  lo = __builtin_amdgcn_cvt_pk_fp8_f32(a.z * inv, a.w * inv, lo, true);
  hi = __builtin_amdgcn_cvt_pk_fp8_f32(b.x * inv, b.y * inv, hi, false);
  hi = __builtin_amdgcn_cvt_pk_fp8_f32(b.z * inv, b.w * inv, hi, true);
  int2 p; p.x = lo; p.y = hi;
  ((int2*)(fQ + (size_t)row * ROWB))[lane] = p;
  if (lane == 0) Z[row] = 0.0f;
}

// ---- K2: fused fp8 similarity + partial softmax-denominator -----------------
// grid (64, 8): blockIdx.x -> 128-row tile, blockIdx.y -> 1024-col j-range
// (8 jt of 128 cols). 4 waves 2x2; wave owns 64x64 C via 4x4 frags of
// 16x16x128 MX-fp8 MFMA (scale=1). K staged in 4 chunks of 128 B/row.
// 16B LDS granules XOR-swizzled by (row&7) on the global source.
__global__ __launch_bounds__(256, 2)
void sim_kernel(const unsigned char* __restrict__ fQ,
                float* __restrict__ Z, float* __restrict__ T01,
                float* __restrict__ D) {
  __shared__ unsigned char ldsA[128 * 128];   // 16 KB
  __shared__ unsigned char ldsB[128 * 128];   // 16 KB

  const int tid = threadIdx.x;
  const int lane = tid & 63;
  const int w = tid >> 6;
  const int wm = w & 1;       // wave row strip (0/1) -> rows wm*64..
  const int wn = w >> 1;      // wave col strip (0/1) -> cols wn*64..
  const int I0 = blockIdx.x * 128;
  const int Jbase = blockIdx.y * 1024;

  // staging lane geometry: 8 rows x 8 granules(16B) per instruction
  const int srow = lane >> 3;                 // 0..7
  const int sg = (lane & 7) ^ srow;           // swizzled source granule
  const size_t sOff = (size_t)srow * ROWB + sg * 16;  // bytes

  // fragment-read lane geometry
  const int fr = lane & 15;   // M/N index within 16
  const int q = lane >> 4;    // quad -> k chunk of 32B
  const int swz = fr & 7;     // row&7 of the frag row

  // precomputed LDS frag base pointers (byte addresses)
  const unsigned char* raBase = ldsA + (wm * 64 + fr) * 128;
  const unsigned char* rbBase = ldsB + (wn * 64 + fr) * 128;
  const int off0 = ((2 * q) ^ swz) * 16;
  const int off1 = ((2 * q + 1) ^ swz) * 16;

  float Zp[4][4];
#pragma unroll
  for (int m = 0; m < 4; ++m)
#pragma unroll
    for (int r = 0; r < 4; ++r) Zp[m][r] = 0.0f;

  for (int jt = 0; jt < 8; ++jt) {
    const int J0 = Jbase + jt * 128;
    f32x4 acc[4][4];
#pragma unroll
    for (int m = 0; m < 4; ++m)
#pragma unroll
      for (int n = 0; n < 4; ++n) acc[m][n] = (f32x4){0.f, 0.f, 0.f, 0.f};

    for (int kk = 0; kk < 4; ++kk) {
      const int k0 = kk * 128;  // byte offset into row
      {  // A: 128 rows, wave stages rows w*32..+31 (4 instrs)
        const unsigned char* gA = fQ + (size_t)(I0 + w * 32) * ROWB + k0 + sOff;
        unsigned char* lA = ldsA + (w * 32) * 128;
#pragma unroll
        for (int rr = 0; rr < 32; rr += 8)
          load16_to_lds(gA + (size_t)rr * ROWB, lA + rr * 128);
      }
      {  // B: 128 rows, wave stages rows w*32..+31 (4 instrs)
        const unsigned char* gB = fQ + (size_t)(J0 + w * 32) * ROWB + k0 + sOff;
        unsigned char* lB = ldsB + (w * 32) * 128;
#pragma unroll
        for (int rr = 0; rr < 32; rr += 8)
          load16_to_lds(gB + (size_t)rr * ROWB, lB + rr * 128);
      }
      __syncthreads();

      i32x8 av[4], bv[4];
#pragma unroll
      for (int m = 0; m < 4; ++m) {
        const unsigned char* ra = raBase + m * 16 * 128;
        int4 r0 = *(const int4*)(ra + off0);
        int4 r1 = *(const int4*)(ra + off1);
        av[m] = (i32x8){r0.x, r0.y, r0.z, r0.w, r1.x, r1.y, r1.z, r1.w};
      }
#pragma unroll
      for (int n = 0; n < 4; ++n) {
        const unsigned char* rb = rbBase + n * 16 * 128;
        int4 r0 = *(const int4*)(rb + off0);
        int4 r1 = *(const int4*)(rb + off1);
        bv[n] = (i32x8){r0.x, r0.y, r0.z, r0.w, r1.x, r1.y, r1.z, r1.w};
      }
#pragma unroll
      for (int m = 0; m < 4; ++m)
#pragma unroll
        for (int n = 0; n < 4; ++n)
          acc[m][n] = __builtin_amdgcn_mfma_scale_f32_16x16x128_f8f6f4(
              av[m], bv[n], acc[m][n], 0, 0, 0, 127, 0, 127);
      __syncthreads();
    }

    // capture sim[:,0] and sim[:,1] (cols 0,1: j-tile 0, wn==0, n==0, fr<2)
    if (blockIdx.y == 0 && jt == 0 && wn == 0 && fr < 2) {
#pragma unroll
      for (int m = 0; m < 4; ++m)
#pragma unroll
        for (int r = 0; r < 4; ++r) {
          const int row = I0 + wm * 64 + m * 16 + q * 4 + r;
          T01[row * 2 + fr] = acc[m][0][r] * INVT;
        }
    }

    // capture the computed diagonal dot (for exact-diag correction)
    if (blockIdx.y == (blockIdx.x >> 3) && jt == (blockIdx.x & 7)) {
#pragma unroll
      for (int m = 0; m < 4; ++m)
#pragma unroll
        for (int n = 0; n < 4; ++n) {
          const int col = J0 + wn * 64 + n * 16 + fr;
#pragma unroll
          for (int r = 0; r < 4; ++r) {
            const int row = I0 + wm * 64 + m * 16 + q * 4 + r;
            if (row == col) D[row] = acc[m][n][r];
          }
        }
    }

    // Z partials: exp((dot-1)/T) summed over this wave's 64 cols
#pragma unroll
    for (int m = 0; m < 4; ++m)
#pragma unroll
      for (int n = 0; n < 4; ++n)
#pragma unroll
        for (int r = 0; r < 4; ++r)
          Zp[m][r] += exp2f((acc[m][n][r] - 1.0f) * SCALE_LOG2);
  }

  // reduce Zp across the 16 col-lanes (low 4 lane bits), then atomicAdd
#pragma unroll
  for (int m = 0; m < 4; ++m)
#pragma unroll
    for (int r = 0; r < 4; ++r) {
      float v = Zp[m][r];
      v += __shfl_xor(v, 1);
      v += __shfl_xor(v, 2);
      v += __shfl_xor(v, 4);
      v += __shfl_xor(v, 8);
      if (fr == 0) atomicAdd(&Z[I0 + wm * 64 + m * 16 + q * 4 + r], v);
    }
}

// ---- K3: labels + exact-diagonal fixup + final loss reduction ---------------
__global__ __launch_bounds__(1024)
void finalize_kernel(const float* __restrict__ Z,
                     const float* __restrict__ T01,
                     const float* __restrict__ D,
                     const int* __restrict__ ids,
                     const int* __restrict__ anchor,
                     float* __restrict__ out) {
  __shared__ float red[1024];
  const int t = threadIdx.x;
  const int anchor_id = ids[anchor[0]];
  const int sameLast = (ids[B_N - 1] == anchor_id);
  const int samePrev = (ids[B_N - 2] == anchor_id);
  float sum = 0.0f;
#pragma unroll
  for (int it = 0; it < B_N / 1024; ++it) {
    const int i = it * 1024 + t;
    const int same_i = (ids[i] == anchor_id);
    const int lab = (i < B_N - 1) ? (same_i & sameLast) : (sameLast & samePrev);
    const float tt = T01[i * 2 + lab];
    // replace quantized diag contribution with the exact value exp(0)=1
    const float Zc = Z[i] - exp2f((D[i] - 1.0f) * SCALE_LOG2) + 1.0f;
    sum += tt - (INVT + logf(Zc));
  }
  red[t] = sum;
  __syncthreads();
  for (int off = 512; off > 0; off >>= 1) {
    if (t < off) red[t] += red[t + off];
    __syncthreads();
  }
  if (t == 0) out[0] = -red[0] / (float)B_N;
}

// ---------------------------------------------------------------------------
extern "C" void kernel_launch(void* const* d_in, const int* in_sizes, int n_in,
                              void* d_out, int out_size, void* d_ws, size_t ws_size,
                              hipStream_t stream) {
  const float* x = (const float*)d_in[0];
  const int* ids = (const int*)d_in[1];
  const int* anchor = (const int*)d_in[2];
  float* out = (float*)d_out;

  unsigned char* fQ = (unsigned char*)d_ws;                    // 4 MB fp8
  float* Z = (float*)((char*)d_ws + (size_t)B_N * ROWB);       // 32 KB
  float* T01 = Z + B_N;                                        // 64 KB
  float* D = T01 + 2 * B_N;                                    // 32 KB

  norm_kernel<<<B_N / 4, 256, 0, stream>>>(x, fQ, Z);
  sim_kernel<<<dim3(64, 8), 256, 0, stream>>>(fQ, Z, T01, D);
  finalize_kernel<<<1, 1024, 0, stream>>>(Z, T01, D, ids, anchor, out);
}

// Round 6
// 122.728 us; speedup vs baseline: 2.9848x; 1.6187x over previous
//
#include <hip/hip_runtime.h>

// ---------------------------------------------------------------------------
// VisualContrastiveLoss on MI355X
// loss = C + mean_i log(Z_i) - mean_i sim[i, lab_i],  C = 1/0.07
//   Z_i = sum_j exp(sim_ij - C)   (fixed shift: dots bounded by 1)
//   sim = (f f^T)/0.07, f = row-normalized visual_feat
// R6: MX-fp8 (e4m3, scale=1) via mfma_scale_f32_16x16x128_f8f6f4.
//     Spill fix: R3-R5 scratch traffic (~150-520 MB) was invariant to
//     fragment-split edits -> compiler fully unrolled jt x kk and hoisted all
//     staging addresses, blowing the 128 arch-VGPR side. Fix: #pragma unroll 1
//     on jt/kk loops + m-split frag loads (bv[4]+av[2] = 48 live frag regs).
//     Wave tile 64x64 (acc[4][4]=64 AGPR), block 128x128, grid (64,8).
//     Exact-diagonal correction via captured D[i] (validated R3-R5).
// ---------------------------------------------------------------------------

typedef int i32x8 __attribute__((ext_vector_type(8)));
typedef float f32x4 __attribute__((ext_vector_type(4)));

#define B_N 8192
#define D_K 512
#define ROWB 512  // bytes per fp8 row
#define INVT 14.285714285714286f
// (1/0.07) * log2(e)
#define SCALE_LOG2 20.609929155556622f

static __device__ __forceinline__ void load16_to_lds(const void* g, void* l) {
  __builtin_amdgcn_global_load_lds(
      (const __attribute__((address_space(1))) unsigned int*)g,
      (__attribute__((address_space(3))) unsigned int*)l, 16, 0, 0);
}

// ---- K1: 4 waves/block, one wave per row; normalize fp32 -> fp8 e4m3 --------
__global__ __launch_bounds__(256)
void norm_kernel(const float* __restrict__ x,
                 unsigned char* __restrict__ fQ,
                 float* __restrict__ Z) {
  const int row = blockIdx.x * 4 + (threadIdx.x >> 6);
  const int lane = threadIdx.x & 63;
  const float4* xr = (const float4*)(x + (size_t)row * D_K);
  float4 a = xr[2 * lane];
  float4 b = xr[2 * lane + 1];
  float s = a.x * a.x + a.y * a.y + a.z * a.z + a.w * a.w +
            b.x * b.x + b.y * b.y + b.z * b.z + b.w * b.w;
#pragma unroll
  for (int off = 1; off < 64; off <<= 1) s += __shfl_xor(s, off);
  const float inv = 1.0f / fmaxf(sqrtf(s), 1e-12f);
  int lo = 0, hi = 0;
  lo = __builtin_amdgcn_cvt_pk_fp8_f32(a.x * inv, a.y * inv, lo, false);
  lo = __builtin_amdgcn_cvt_pk_fp8_f32(a.z * inv, a.w * inv, lo, true);
  hi = __builtin_amdgcn_cvt_pk_fp8_f32(b.x * inv, b.y * inv, hi, false);
  hi = __builtin_amdgcn_cvt_pk_fp8_f32(b.z * inv, b.w * inv, hi, true);
  int2 p; p.x = lo; p.y = hi;
  ((int2*)(fQ + (size_t)row * ROWB))[lane] = p;
  if (lane == 0) Z[row] = 0.0f;
}

// ---- K2: fused fp8 similarity + partial softmax-denominator -----------------
// grid (64, 8): blockIdx.x -> 128-row tile, blockIdx.y -> 1024-col j-range
// (8 jt of 128 cols). 4 waves 2x2; wave owns 64x64 C via 4x4 frags of
// 16x16x128 MX-fp8 MFMA (scale=1). K staged in 4 chunks of 128 B/row.
// 16B LDS granules XOR-swizzled by (row&7) on the global source.
__global__ __launch_bounds__(256, 2)
void sim_kernel(const unsigned char* __restrict__ fQ,
                float* __restrict__ Z, float* __restrict__ T01,
                float* __restrict__ D) {
  __shared__ unsigned char ldsA[128 * 128];   // 16 KB
  __shared__ unsigned char ldsB[128 * 128];   // 16 KB

  const int tid = threadIdx.x;
  const int lane = tid & 63;
  const int w = tid >> 6;
  const int wm = w & 1;       // wave row strip (0/1) -> rows wm*64..
  const int wn = w >> 1;      // wave col strip (0/1) -> cols wn*64..
  const int I0 = blockIdx.x * 128;
  const int Jbase = blockIdx.y * 1024;

  // staging lane geometry: 8 rows x 8 granules(16B) per instruction
  const int srow = lane >> 3;                 // 0..7
  const int sg = (lane & 7) ^ srow;           // swizzled source granule
  const size_t sOff = (size_t)srow * ROWB + sg * 16;  // bytes

  // fragment-read lane geometry
  const int fr = lane & 15;   // M/N index within 16
  const int q = lane >> 4;    // quad -> k chunk of 32B
  const int swz = fr & 7;     // row&7 of the frag row

  // precomputed LDS frag base pointers (byte addresses)
  const unsigned char* raBase = ldsA + (wm * 64 + fr) * 128;
  const unsigned char* rbBase = ldsB + (wn * 64 + fr) * 128;
  const int off0 = ((2 * q) ^ swz) * 16;
  const int off1 = ((2 * q + 1) ^ swz) * 16;

  float Zp[4][4];
#pragma unroll
  for (int m = 0; m < 4; ++m)
#pragma unroll
    for (int r = 0; r < 4; ++r) Zp[m][r] = 0.0f;

#pragma unroll 1
  for (int jt = 0; jt < 8; ++jt) {
    const int J0 = Jbase + jt * 128;
    f32x4 acc[4][4];
#pragma unroll
    for (int m = 0; m < 4; ++m)
#pragma unroll
      for (int n = 0; n < 4; ++n) acc[m][n] = (f32x4){0.f, 0.f, 0.f, 0.f};

#pragma unroll 1
    for (int kk = 0; kk < 4; ++kk) {
      const int k0 = kk * 128;  // byte offset into row
      {  // A: 128 rows, wave stages rows w*32..+31 (4 instrs)
        const unsigned char* gA = fQ + (size_t)(I0 + w * 32) * ROWB + k0 + sOff;
        unsigned char* lA = ldsA + (w * 32) * 128;
#pragma unroll
        for (int rr = 0; rr < 32; rr += 8)
          load16_to_lds(gA + (size_t)rr * ROWB, lA + rr * 128);
      }
      {  // B: 128 rows, wave stages rows w*32..+31 (4 instrs)
        const unsigned char* gB = fQ + (size_t)(J0 + w * 32) * ROWB + k0 + sOff;
        unsigned char* lB = ldsB + (w * 32) * 128;
#pragma unroll
        for (int rr = 0; rr < 32; rr += 8)
          load16_to_lds(gB + (size_t)rr * ROWB, lB + rr * 128);
      }
      __syncthreads();

      i32x8 bv[4];
#pragma unroll
      for (int n = 0; n < 4; ++n) {
        const unsigned char* rb = rbBase + n * 16 * 128;
        int4 r0 = *(const int4*)(rb + off0);
        int4 r1 = *(const int4*)(rb + off1);
        bv[n] = (i32x8){r0.x, r0.y, r0.z, r0.w, r1.x, r1.y, r1.z, r1.w};
      }
#pragma unroll
      for (int mh = 0; mh < 2; ++mh) {  // m-split: av[2] live, not av[4]
        i32x8 av[2];
#pragma unroll
        for (int m = 0; m < 2; ++m) {
          const unsigned char* ra = raBase + (mh * 2 + m) * 16 * 128;
          int4 r0 = *(const int4*)(ra + off0);
          int4 r1 = *(const int4*)(ra + off1);
          av[m] = (i32x8){r0.x, r0.y, r0.z, r0.w, r1.x, r1.y, r1.z, r1.w};
        }
#pragma unroll
        for (int m = 0; m < 2; ++m)
#pragma unroll
          for (int n = 0; n < 4; ++n)
            acc[mh * 2 + m][n] = __builtin_amdgcn_mfma_scale_f32_16x16x128_f8f6f4(
                av[m], bv[n], acc[mh * 2 + m][n], 0, 0, 0, 127, 0, 127);
      }
      __syncthreads();
    }

    // capture sim[:,0] and sim[:,1] (cols 0,1: j-tile 0, wn==0, n==0, fr<2)
    if (blockIdx.y == 0 && jt == 0 && wn == 0 && fr < 2) {
#pragma unroll
      for (int m = 0; m < 4; ++m)
#pragma unroll
        for (int r = 0; r < 4; ++r) {
          const int row = I0 + wm * 64 + m * 16 + q * 4 + r;
          T01[row * 2 + fr] = acc[m][0][r] * INVT;
        }
    }

    // capture the computed diagonal dot (for exact-diag correction)
    if (blockIdx.y == (blockIdx.x >> 3) && jt == (blockIdx.x & 7)) {
#pragma unroll
      for (int m = 0; m < 4; ++m)
#pragma unroll
        for (int n = 0; n < 4; ++n) {
          const int col = J0 + wn * 64 + n * 16 + fr;
#pragma unroll
          for (int r = 0; r < 4; ++r) {
            const int row = I0 + wm * 64 + m * 16 + q * 4 + r;
            if (row == col) D[row] = acc[m][n][r];
          }
        }
    }

    // Z partials: exp((dot-1)/T) summed over this wave's 64 cols
#pragma unroll
    for (int m = 0; m < 4; ++m)
#pragma unroll
      for (int n = 0; n < 4; ++n)
#pragma unroll
        for (int r = 0; r < 4; ++r)
          Zp[m][r] += exp2f((acc[m][n][r] - 1.0f) * SCALE_LOG2);
  }

  // reduce Zp across the 16 col-lanes (low 4 lane bits), then atomicAdd
#pragma unroll
  for (int m = 0; m < 4; ++m)
#pragma unroll
    for (int r = 0; r < 4; ++r) {
      float v = Zp[m][r];
      v += __shfl_xor(v, 1);
      v += __shfl_xor(v, 2);
      v += __shfl_xor(v, 4);
      v += __shfl_xor(v, 8);
      if (fr == 0) atomicAdd(&Z[I0 + wm * 64 + m * 16 + q * 4 + r], v);
    }
}

// ---- K3: labels + exact-diagonal fixup + final loss reduction ---------------
__global__ __launch_bounds__(1024)
void finalize_kernel(const float* __restrict__ Z,
                     const float* __restrict__ T01,
                     const float* __restrict__ D,
                     const int* __restrict__ ids,
                     const int* __restrict__ anchor,
                     float* __restrict__ out) {
  __shared__ float red[1024];
  const int t = threadIdx.x;
  const int anchor_id = ids[anchor[0]];
  const int sameLast = (ids[B_N - 1] == anchor_id);
  const int samePrev = (ids[B_N - 2] == anchor_id);
  float sum = 0.0f;
#pragma unroll
  for (int it = 0; it < B_N / 1024; ++it) {
    const int i = it * 1024 + t;
    const int same_i = (ids[i] == anchor_id);
    const int lab = (i < B_N - 1) ? (same_i & sameLast) : (sameLast & samePrev);
    const float tt = T01[i * 2 + lab];
    // replace quantized diag contribution with the exact value exp(0)=1
    const float Zc = Z[i] - exp2f((D[i] - 1.0f) * SCALE_LOG2) + 1.0f;
    sum += tt - (INVT + logf(Zc));
  }
  red[t] = sum;
  __syncthreads();
  for (int off = 512; off > 0; off >>= 1) {
    if (t < off) red[t] += red[t + off];
    __syncthreads();
  }
  if (t == 0) out[0] = -red[0] / (float)B_N;
}

// ---------------------------------------------------------------------------
extern "C" void kernel_launch(void* const* d_in, const int* in_sizes, int n_in,
                              void* d_out, int out_size, void* d_ws, size_t ws_size,
                              hipStream_t stream) {
  const float* x = (const float*)d_in[0];
  const int* ids = (const int*)d_in[1];
  const int* anchor = (const int*)d_in[2];
  float* out = (float*)d_out;

  unsigned char* fQ = (unsigned char*)d_ws;                    // 4 MB fp8
  float* Z = (float*)((char*)d_ws + (size_t)B_N * ROWB);       // 32 KB
  float* T01 = Z + B_N;                                        // 64 KB
  float* D = T01 + 2 * B_N;                                    // 32 KB

  norm_kernel<<<B_N / 4, 256, 0, stream>>>(x, fQ, Z);
  sim_kernel<<<dim3(64, 8), 256, 0, stream>>>(fQ, Z, T01, D);
  finalize_kernel<<<1, 1024, 0, stream>>>(Z, T01, D, ids, anchor, out);
}